// Round 2
// baseline (299.876 us; speedup 1.0000x reference)
//
#include <hip/hip_runtime.h>
#include <cstdint>
#include <cstddef>

// ---------------------------------------------------------------------------
// LSTM cell: gates = [x|h] (2048x4096) · [W_ih|W_hh]^T (8192x4096) + b
// fp32->bf16 pack -> bf16 MFMA GEMM (128² tile, ring-4 counted-vmcnt) -> epi
// ---------------------------------------------------------------------------

typedef __attribute__((ext_vector_type(8))) short bf16x8;
typedef __attribute__((ext_vector_type(4))) float f32x4;

#define GLD_AS1 const __attribute__((address_space(1))) void
#define GLD_AS3 __attribute__((address_space(3))) void

__device__ __forceinline__ void gload_lds16(const void* g, void* l) {
  __builtin_amdgcn_global_load_lds((GLD_AS1*)g, (GLD_AS3*)l, 16, 0, 0);
}

__device__ __forceinline__ unsigned short f2bf(float f) {
  unsigned int u = __float_as_uint(f);
  unsigned int r = 0x7FFFu + ((u >> 16) & 1u);
  return (unsigned short)((u + r) >> 16);
}

// two-sided compiler fence + hardware barrier (no vmcnt drain)
__device__ __forceinline__ void block_barrier() {
  asm volatile("" ::: "memory");
  __builtin_amdgcn_s_barrier();
  asm volatile("" ::: "memory");
}

// ---- pack fp32 (rows x 2048) into bf16 (rows x 4096) at column offset -----
__global__ __launch_bounds__(256) void cvt2048(const float* __restrict__ src,
                                               unsigned short* __restrict__ dst,
                                               int col_off, int total4) {
  int i = blockIdx.x * 256 + threadIdx.x;
  if (i >= total4) return;
  int flat = i << 2;
  int r = flat >> 11;
  int c = flat & 2047;
  float4 v = *(const float4*)(src + flat);
  ushort4 o;
  o.x = f2bf(v.x); o.y = f2bf(v.y); o.z = f2bf(v.z); o.w = f2bf(v.w);
  *(ushort4*)(dst + (((size_t)r) << 12) + col_off + c) = o;
}

// ---- bf16 GEMM: gates[2048x8192] = A[2048x4096] * W[8192x4096]^T + bias ---
// 128x128 tile, BK=32, 256 threads (4 waves 2x2), ring-4 LDS, counted vmcnt
__global__ __launch_bounds__(256) void gemm_gates(
    const unsigned short* __restrict__ A,   // [2048][4096] bf16
    const unsigned short* __restrict__ W,   // [8192][4096] bf16
    const float* __restrict__ b_ih, const float* __restrict__ b_hh,
    float* __restrict__ gates)              // [2048][8192] fp32
{
  constexpr int N = 8192, K = 4096;
  constexpr int BK = 32;
  constexpr int NT = K / BK;                // 128 K-tiles
  __shared__ alignas(16) unsigned short As[4][128 * BK];  // 4 x 8 KiB
  __shared__ alignas(16) unsigned short Bs[4][128 * BK];  // 4 x 8 KiB

  // XCD-slab mapping: XCD x owns bn columns 8x..8x+7, all 16 bm rows.
  // b = (hi<<7)|(mid<<3)|x  ->  bm=mid, bn_col=8x+hi  (bijective)
  int b = blockIdx.x;
  int bm = ((b >> 3) & 15) * 128;
  int bn = (((b & 7) << 3) + (b >> 7)) * 128;

  int tid  = threadIdx.x;
  int lane = tid & 63;
  int w    = tid >> 6;
  int wm   = (w >> 1) * 64;
  int wn   = (w & 1) * 64;

  f32x4 acc[4][4] = {};

  // staging geometry: per wave 2 chunks of 16 rows; lane -> (row, col8)
  int chunk0 = w * 2;
  int srow = chunk0 * 16 + (lane >> 2);
  int scol = (lane & 3) * 8;
  const unsigned short* gA = A + (size_t)(bm + srow) * K + scol;
  const unsigned short* gB = W + (size_t)(bn + srow) * K + scol;

  // per-thread per-tile: 4 gloads (A0,A1,B0,B1) in fixed order
  auto stage = [&](int t) {
    int s = t & 3;
    int k0 = t * BK;
    gload_lds16(gA + k0,                    &As[s][chunk0 * 512]);
    gload_lds16(gA + k0 + (size_t)16 * K,   &As[s][(chunk0 + 1) * 512]);
    gload_lds16(gB + k0,                    &Bs[s][chunk0 * 512]);
    gload_lds16(gB + k0 + (size_t)16 * K,   &Bs[s][(chunk0 + 1) * 512]);
  };

  auto compute = [&](int t) {
    int s = t & 3;
    bf16x8 af[4], bfr[4];
#pragma unroll
    for (int mf = 0; mf < 4; ++mf)
      af[mf] = *(const bf16x8*)&As[s][(wm + mf * 16 + (lane & 15)) * BK + (lane >> 4) * 8];
#pragma unroll
    for (int nf = 0; nf < 4; ++nf)
      bfr[nf] = *(const bf16x8*)&Bs[s][(wn + nf * 16 + (lane & 15)) * BK + (lane >> 4) * 8];
    __builtin_amdgcn_s_setprio(1);
#pragma unroll
    for (int mf = 0; mf < 4; ++mf)
#pragma unroll
      for (int nf = 0; nf < 4; ++nf)
        acc[mf][nf] = __builtin_amdgcn_mfma_f32_16x16x32_bf16(af[mf], bfr[nf], acc[mf][nf], 0, 0, 0);
    __builtin_amdgcn_s_setprio(0);
  };

  // prologue: 3 tiles in flight
  stage(0); stage(1); stage(2);

  for (int t = 0; t < NT - 3; ++t) {
    stage(t + 3);
    asm volatile("s_waitcnt vmcnt(12)" ::: "memory");   // tile t landed
    block_barrier();
    compute(t);
    block_barrier();
  }
  asm volatile("s_waitcnt vmcnt(8)" ::: "memory");
  block_barrier();
  compute(NT - 3);
  block_barrier();
  asm volatile("s_waitcnt vmcnt(4)" ::: "memory");
  block_barrier();
  compute(NT - 2);
  block_barrier();
  asm volatile("s_waitcnt vmcnt(0)" ::: "memory");
  block_barrier();
  compute(NT - 1);

  // C-write + fused bias. C/D layout: col=lane&15, row=(lane>>4)*4+j (m89)
#pragma unroll
  for (int nf = 0; nf < 4; ++nf) {
    int col = bn + wn + nf * 16 + (lane & 15);
    float bias = b_ih[col] + b_hh[col];
#pragma unroll
    for (int mf = 0; mf < 4; ++mf) {
      int row0 = bm + wm + mf * 16 + (lane >> 4) * 4;
#pragma unroll
      for (int j = 0; j < 4; ++j)
        gates[(size_t)(row0 + j) * N + col] = acc[mf][nf][j] + bias;
    }
  }
}

// ---- elementwise LSTM epilogue --------------------------------------------
__device__ __forceinline__ float sigm(float x) { return 1.0f / (1.0f + __expf(-x)); }

__global__ __launch_bounds__(256) void lstm_epi(const float* __restrict__ gates,
                                                const float* __restrict__ C_prev,
                                                float* __restrict__ out, int total4) {
  int i = blockIdx.x * 256 + threadIdx.x;
  if (i >= total4) return;
  int flat = i << 2;
  int b = flat >> 11;
  int h = flat & 2047;
  const float* grow = gates + (((size_t)b) << 13);
  float4 vi = *(const float4*)(grow + h);
  float4 vf = *(const float4*)(grow + 2048 + h);
  float4 vg = *(const float4*)(grow + 4096 + h);
  float4 vo = *(const float4*)(grow + 6144 + h);
  float4 cp = *(const float4*)(C_prev + flat);

  float4 nh, nc, fg, ig, gg, og;
  const float* pi = (const float*)&vi;
  const float* pf = (const float*)&vf;
  const float* pg = (const float*)&vg;
  const float* po = (const float*)&vo;
  const float* pc = (const float*)&cp;
  float* onh = (float*)&nh; float* onc = (float*)&nc;
  float* ofg = (float*)&fg; float* oig = (float*)&ig;
  float* ogg = (float*)&gg; float* oog = (float*)&og;
#pragma unroll
  for (int j = 0; j < 4; ++j) {
    float I = sigm(pi[j]);
    float F = sigm(pf[j]);
    float G = tanhf(pg[j]);
    float O = sigm(po[j]);
    float C = F * pc[j] + I * G;
    float H = O * tanhf(C);
    oig[j] = I; ofg[j] = F; ogg[j] = G; oog[j] = O; onc[j] = C; onh[j] = H;
  }
  constexpr size_t SEC = (size_t)2048 * 2048;
  *(float4*)(out + 0 * SEC + flat) = nh;
  *(float4*)(out + 1 * SEC + flat) = nc;
  *(float4*)(out + 2 * SEC + flat) = fg;
  *(float4*)(out + 3 * SEC + flat) = ig;
  *(float4*)(out + 4 * SEC + flat) = gg;
  *(float4*)(out + 5 * SEC + flat) = og;
}

// ---------------------------------------------------------------------------
extern "C" void kernel_launch(void* const* d_in, const int* in_sizes, int n_in,
                              void* d_out, int out_size, void* d_ws, size_t ws_size,
                              hipStream_t stream) {
  const float* x   = (const float*)d_in[0];
  const float* h   = (const float*)d_in[1];
  const float* Cp  = (const float*)d_in[2];
  const float* Wih = (const float*)d_in[3];
  const float* bih = (const float*)d_in[4];
  const float* Whh = (const float*)d_in[5];
  const float* bhh = (const float*)d_in[6];
  float* out = (float*)d_out;

  uint8_t* ws = (uint8_t*)d_ws;
  unsigned short* Abf  = (unsigned short*)ws;                          // 16 MiB
  unsigned short* Wbf  = (unsigned short*)(ws + (size_t)(16u << 20));  // 64 MiB
  float*          gates = (float*)(ws + (size_t)(80u << 20));          // 64 MiB

  cvt2048<<<4096, 256, 0, stream>>>(x, Abf, 0,    1048576);
  cvt2048<<<4096, 256, 0, stream>>>(h, Abf, 2048, 1048576);
  cvt2048<<<16384, 256, 0, stream>>>(Wih, Wbf, 0,    4194304);
  cvt2048<<<16384, 256, 0, stream>>>(Whh, Wbf, 2048, 4194304);

  gemm_gates<<<1024, 256, 0, stream>>>(Abf, Wbf, bih, bhh, gates);

  lstm_epi<<<4096, 256, 0, stream>>>(gates, Cp, out, 1048576);
}

// Round 3
// 195.601 us; speedup vs baseline: 1.5331x; 1.5331x over previous
//
#include <hip/hip_runtime.h>
#include <cstdint>
#include <cstddef>

// ---------------------------------------------------------------------------
// LSTM cell: gates = [x|h] (2048x4096) · [W_ih|W_hh]^T (8192x4096) + b
// fp32->bf16 pack -> 256² 8-phase bf16 MFMA GEMM (m201 template) -> epilogue
// ---------------------------------------------------------------------------

typedef __attribute__((ext_vector_type(8))) short bf16x8;
typedef __attribute__((ext_vector_type(4))) float f32x4;

#define GLD_AS1 const __attribute__((address_space(1))) void
#define GLD_AS3 __attribute__((address_space(3))) void

__device__ __forceinline__ void gload_lds16(const void* g, void* l) {
  __builtin_amdgcn_global_load_lds((GLD_AS1*)g, (GLD_AS3*)l, 16, 0, 0);
}

__device__ __forceinline__ unsigned short f2bf(float f) {
  unsigned int u = __float_as_uint(f);
  unsigned int r = 0x7FFFu + ((u >> 16) & 1u);
  return (unsigned short)((u + r) >> 16);
}

__device__ __forceinline__ void barrier_f() {
  asm volatile("" ::: "memory");
  __builtin_amdgcn_s_barrier();
  asm volatile("" ::: "memory");
}

// ---- merged pack: fp32 (rows x 2048) -> bf16 (rows x 4096 at col off) -----
// blocks: [0,4096) x->A+0 | [4096,8192) h->A+2048 | [8192,24576) Wih->W+0
//         | [24576,40960) Whh->W+2048
__global__ __launch_bounds__(256) void cvt_all(const float* __restrict__ x,
                                               const float* __restrict__ h,
                                               const float* __restrict__ Wih,
                                               const float* __restrict__ Whh,
                                               unsigned short* __restrict__ Abf,
                                               unsigned short* __restrict__ Wbf) {
  int bid = blockIdx.x;
  const float* src; unsigned short* dst; int col_off; int base;
  if (bid < 4096)        { src = x;   dst = Abf; col_off = 0;    base = bid; }
  else if (bid < 8192)   { src = h;   dst = Abf; col_off = 2048; base = bid - 4096; }
  else if (bid < 24576)  { src = Wih; dst = Wbf; col_off = 0;    base = bid - 8192; }
  else                   { src = Whh; dst = Wbf; col_off = 2048; base = bid - 24576; }
  int i = base * 256 + threadIdx.x;
  int flat = i << 2;
  int r = flat >> 11;
  int c = flat & 2047;
  float4 v = *(const float4*)(src + flat);
  ushort4 o;
  o.x = f2bf(v.x); o.y = f2bf(v.y); o.z = f2bf(v.z); o.w = f2bf(v.w);
  *(ushort4*)(dst + (((size_t)r) << 12) + col_off + c) = o;
}

// ---- 256² 8-phase bf16 GEMM ----------------------------------------------
// gates[2048x8192] = A[2048x4096] * W[8192x4096]^T + bias
// BM=BN=256, BK=64, 512 threads (2M x 4N waves), per-wave 128x64 output.
// LDS 128 KiB: lds[buf2][part4][128*64], parts {A0,A1,B0,B1} (halves).
// Swizzle: colbyte ^= (row&7)<<4, applied on global SOURCE (stage) and READ.
// Stagger: tile t phases stage {A0(t+1),A1(t+1),B0(t+2),B1(t+2)} -> vmcnt(4).
__global__ __launch_bounds__(512, 2) void gemm_gates(
    const unsigned short* __restrict__ A,   // [2048][4096] bf16
    const unsigned short* __restrict__ W,   // [8192][4096] bf16
    const float* __restrict__ b_ih, const float* __restrict__ b_hh,
    float* __restrict__ gates)              // [2048][8192] fp32
{
  constexpr int N = 8192, K = 4096;
  constexpr int BK = 64;
  constexpr int NT = K / BK;                // 64 K-tiles
  __shared__ alignas(16) unsigned short lds[2][4][128 * 64];  // 128 KiB

  // XCD slab: x owns 4 bn-tiles x all 8 bm-tiles (disjoint 8MB W slab)
  int b  = blockIdx.x;
  int xc = b & 7, ii = b >> 3;
  int bm = (ii & 7) * 256;
  int bn = (xc * 4 + (ii >> 3)) * 256;

  int tid  = threadIdx.x;
  int lane = tid & 63;
  int w    = tid >> 6;        // 0..7
  int wm   = w >> 2;          // 0..1 -> A-half
  int wn   = w & 3;           // 0..3 -> B-half wn>>1, sub-row (wn&1)*64
  int l15  = lane & 15;
  int lq   = lane >> 4;       // 0..3

  // swizzled fragment col (elements) for kq=0,1: colbyte = kq*64+lq*16
  int ce0 = ((lq * 16) ^ ((l15 & 7) << 4)) >> 1;
  int ce1 = ((64 + lq * 16) ^ ((l15 & 7) << 4)) >> 1;

  // staging: wave w writes chunks {2w,2w+1} (rows 16w..16w+15 of a half);
  // lane source pre-swizzled: row_local = 16w + (lane>>3), col = ((l&7)^(l>>3))*8
  int srow = 16 * w + (lane >> 3);
  int scol = ((lane & 7) ^ (lane >> 3)) * 8;
  const unsigned short* gA = A + (size_t)(bm + srow) * K + scol;
  const unsigned short* gB = W + (size_t)(bn + srow) * K + scol;

  f32x4 acc[8][4] = {};

  auto stageA = [&](int t, int h) {
    unsigned short* l0 = &lds[t & 1][h][w * 1024];
    const unsigned short* g = gA + (size_t)h * 128 * K + t * BK;
    gload_lds16(g, l0);
    gload_lds16(g + (size_t)8 * K, l0 + 512);
  };
  auto stageB = [&](int t, int h) {
    unsigned short* l0 = &lds[t & 1][2 + h][w * 1024];
    const unsigned short* g = gB + (size_t)h * 128 * K + t * BK;
    gload_lds16(g, l0);
    gload_lds16(g + (size_t)8 * K, l0 + 512);
  };

  // prologue: tile0 all halves + tile1 B halves (12 loads/thread)
  stageA(0, 0); stageA(0, 1); stageB(0, 0); stageB(0, 1);
  stageB(1, 0); stageB(1, 1);

  bf16x8 af[4][2], bf01[2][2], bf23[2][2];

  for (int t = 0; t < NT; ++t) {
    if (t < NT - 1) asm volatile("s_waitcnt vmcnt(4)" ::: "memory");
    else            asm volatile("s_waitcnt vmcnt(0)" ::: "memory");
    barrier_f();

    const unsigned short* Ab = lds[t & 1][wm];
    const unsigned short* Bb = lds[t & 1][2 + (wn >> 1)];
    int brow = (wn & 1) * 64;

    // ---- P0: read A m0-3 + B n0-1; stage A0(t+1); MFMA m0-3 x n0-1
#pragma unroll
    for (int mt = 0; mt < 4; ++mt) {
      af[mt][0] = *(const bf16x8*)&Ab[(mt * 16 + l15) * 64 + ce0];
      af[mt][1] = *(const bf16x8*)&Ab[(mt * 16 + l15) * 64 + ce1];
    }
#pragma unroll
    for (int nt = 0; nt < 2; ++nt) {
      bf01[nt][0] = *(const bf16x8*)&Bb[(brow + nt * 16 + l15) * 64 + ce0];
      bf01[nt][1] = *(const bf16x8*)&Bb[(brow + nt * 16 + l15) * 64 + ce1];
    }
    if (t + 1 < NT) stageA(t + 1, 0);
    barrier_f();
    __builtin_amdgcn_s_setprio(1);
#pragma unroll
    for (int mt = 0; mt < 4; ++mt)
#pragma unroll
      for (int nt = 0; nt < 2; ++nt) {
        acc[mt][nt] = __builtin_amdgcn_mfma_f32_16x16x32_bf16(af[mt][0], bf01[nt][0], acc[mt][nt], 0, 0, 0);
        acc[mt][nt] = __builtin_amdgcn_mfma_f32_16x16x32_bf16(af[mt][1], bf01[nt][1], acc[mt][nt], 0, 0, 0);
      }
    __builtin_amdgcn_s_setprio(0);
    barrier_f();

    // ---- P1: read B n2-3; stage A1(t+1); MFMA m0-3 x n2-3
#pragma unroll
    for (int nt = 0; nt < 2; ++nt) {
      bf23[nt][0] = *(const bf16x8*)&Bb[(brow + (2 + nt) * 16 + l15) * 64 + ce0];
      bf23[nt][1] = *(const bf16x8*)&Bb[(brow + (2 + nt) * 16 + l15) * 64 + ce1];
    }
    if (t + 1 < NT) stageA(t + 1, 1);
    barrier_f();
    __builtin_amdgcn_s_setprio(1);
#pragma unroll
    for (int mt = 0; mt < 4; ++mt)
#pragma unroll
      for (int nt = 0; nt < 2; ++nt) {
        acc[mt][2 + nt] = __builtin_amdgcn_mfma_f32_16x16x32_bf16(af[mt][0], bf23[nt][0], acc[mt][2 + nt], 0, 0, 0);
        acc[mt][2 + nt] = __builtin_amdgcn_mfma_f32_16x16x32_bf16(af[mt][1], bf23[nt][1], acc[mt][2 + nt], 0, 0, 0);
      }
    __builtin_amdgcn_s_setprio(0);
    barrier_f();

    // ---- P2: read A m4-7; stage B0(t+2); MFMA m4-7 x n2-3
#pragma unroll
    for (int mt = 0; mt < 4; ++mt) {
      af[mt][0] = *(const bf16x8*)&Ab[(64 + mt * 16 + l15) * 64 + ce0];
      af[mt][1] = *(const bf16x8*)&Ab[(64 + mt * 16 + l15) * 64 + ce1];
    }
    if (t + 2 < NT) stageB(t + 2, 0);
    barrier_f();
    __builtin_amdgcn_s_setprio(1);
#pragma unroll
    for (int mt = 0; mt < 4; ++mt)
#pragma unroll
      for (int nt = 0; nt < 2; ++nt) {
        acc[4 + mt][2 + nt] = __builtin_amdgcn_mfma_f32_16x16x32_bf16(af[mt][0], bf23[nt][0], acc[4 + mt][2 + nt], 0, 0, 0);
        acc[4 + mt][2 + nt] = __builtin_amdgcn_mfma_f32_16x16x32_bf16(af[mt][1], bf23[nt][1], acc[4 + mt][2 + nt], 0, 0, 0);
      }
    __builtin_amdgcn_s_setprio(0);
    barrier_f();

    // ---- P3: stage B1(t+2); MFMA m4-7 x n0-1 (bf01 kept live)
    if (t + 2 < NT) stageB(t + 2, 1);
    barrier_f();
    __builtin_amdgcn_s_setprio(1);
#pragma unroll
    for (int mt = 0; mt < 4; ++mt)
#pragma unroll
      for (int nt = 0; nt < 2; ++nt) {
        acc[4 + mt][nt] = __builtin_amdgcn_mfma_f32_16x16x32_bf16(af[mt][0], bf01[nt][0], acc[4 + mt][nt], 0, 0, 0);
        acc[4 + mt][nt] = __builtin_amdgcn_mfma_f32_16x16x32_bf16(af[mt][1], bf01[nt][1], acc[4 + mt][nt], 0, 0, 0);
      }
    __builtin_amdgcn_s_setprio(0);
    // no trailing barrier: next tile's boundary vmcnt+barrier orders P3.
  }

  // C-write + fused bias. 16x16 C/D: col=lane&15, row=(lane>>4)*4+j (m89)
#pragma unroll
  for (int nt = 0; nt < 4; ++nt) {
    int col = bn + wn * 64 + nt * 16 + l15;
    float bias = b_ih[col] + b_hh[col];
#pragma unroll
    for (int mt = 0; mt < 8; ++mt) {
      int row0 = bm + wm * 128 + mt * 16 + lq * 4;
#pragma unroll
      for (int j = 0; j < 4; ++j)
        gates[(size_t)(row0 + j) * N + col] = acc[mt][nt][j] + bias;
    }
  }
}

// ---- elementwise LSTM epilogue --------------------------------------------
__device__ __forceinline__ float sigm(float x) { return 1.0f / (1.0f + __expf(-x)); }

__global__ __launch_bounds__(256) void lstm_epi(const float* __restrict__ gates,
                                                const float* __restrict__ C_prev,
                                                float* __restrict__ out, int total4) {
  int i = blockIdx.x * 256 + threadIdx.x;
  if (i >= total4) return;
  int flat = i << 2;
  int b = flat >> 11;
  int h = flat & 2047;
  const float* grow = gates + (((size_t)b) << 13);
  float4 vi = *(const float4*)(grow + h);
  float4 vf = *(const float4*)(grow + 2048 + h);
  float4 vg = *(const float4*)(grow + 4096 + h);
  float4 vo = *(const float4*)(grow + 6144 + h);
  float4 cp = *(const float4*)(C_prev + flat);

  float4 nh, nc, fg, ig, gg, og;
  const float* pi = (const float*)&vi;
  const float* pf = (const float*)&vf;
  const float* pg = (const float*)&vg;
  const float* po = (const float*)&vo;
  const float* pc = (const float*)&cp;
  float* onh = (float*)&nh; float* onc = (float*)&nc;
  float* ofg = (float*)&fg; float* oig = (float*)&ig;
  float* ogg = (float*)&gg; float* oog = (float*)&og;
#pragma unroll
  for (int j = 0; j < 4; ++j) {
    float I = sigm(pi[j]);
    float F = sigm(pf[j]);
    float G = tanhf(pg[j]);
    float O = sigm(po[j]);
    float C = F * pc[j] + I * G;
    float H = O * tanhf(C);
    oig[j] = I; ofg[j] = F; ogg[j] = G; oog[j] = O; onc[j] = C; onh[j] = H;
  }
  constexpr size_t SEC = (size_t)2048 * 2048;
  *(float4*)(out + 0 * SEC + flat) = nh;
  *(float4*)(out + 1 * SEC + flat) = nc;
  *(float4*)(out + 2 * SEC + flat) = fg;
  *(float4*)(out + 3 * SEC + flat) = ig;
  *(float4*)(out + 4 * SEC + flat) = gg;
  *(float4*)(out + 5 * SEC + flat) = og;
}

// ---------------------------------------------------------------------------
extern "C" void kernel_launch(void* const* d_in, const int* in_sizes, int n_in,
                              void* d_out, int out_size, void* d_ws, size_t ws_size,
                              hipStream_t stream) {
  const float* x   = (const float*)d_in[0];
  const float* h   = (const float*)d_in[1];
  const float* Cp  = (const float*)d_in[2];
  const float* Wih = (const float*)d_in[3];
  const float* bih = (const float*)d_in[4];
  const float* Whh = (const float*)d_in[5];
  const float* bhh = (const float*)d_in[6];
  float* out = (float*)d_out;

  uint8_t* ws = (uint8_t*)d_ws;
  unsigned short* Abf  = (unsigned short*)ws;                          // 16 MiB
  unsigned short* Wbf  = (unsigned short*)(ws + (size_t)(16u << 20));  // 64 MiB
  float*          gates = (float*)(ws + (size_t)(80u << 20));          // 64 MiB

  cvt_all<<<40960, 256, 0, stream>>>(x, h, Wih, Whh, Abf, Wbf);
  gemm_gates<<<256, 512, 0, stream>>>(Abf, Wbf, bih, bhh, gates);
  lstm_epi<<<4096, 256, 0, stream>>>(gates, Cp, out, 1048576);
}

// Round 4
// 186.599 us; speedup vs baseline: 1.6071x; 1.0482x over previous
//
#include <hip/hip_runtime.h>
#include <cstdint>
#include <cstddef>

// ---------------------------------------------------------------------------
// LSTM cell, fully fused GEMM+epilogue:
//   gates = [x|h] (2048x4096) · [W_ih|W_hh]^T (8192x4096) + b  -> LSTM math
// fp32->bf16 pack -> 256² 8-phase bf16 MFMA GEMM with gate-interleaved
// N-columns; per-lane epilogue computes all 6 outputs. No gates buffer.
// ---------------------------------------------------------------------------

typedef __attribute__((ext_vector_type(8))) short bf16x8;
typedef __attribute__((ext_vector_type(4))) float f32x4;

#define GLD_AS1 const __attribute__((address_space(1))) void
#define GLD_AS3 __attribute__((address_space(3))) void

__device__ __forceinline__ void gload_lds16(const void* g, void* l) {
  __builtin_amdgcn_global_load_lds((GLD_AS1*)g, (GLD_AS3*)l, 16, 0, 0);
}

__device__ __forceinline__ unsigned short f2bf(float f) {
  unsigned int u = __float_as_uint(f);
  unsigned int r = 0x7FFFu + ((u >> 16) & 1u);
  return (unsigned short)((u + r) >> 16);
}

__device__ __forceinline__ void barrier_f() {
  asm volatile("" ::: "memory");
  __builtin_amdgcn_s_barrier();
  asm volatile("" ::: "memory");
}

__device__ __forceinline__ float sigm(float x) { return 1.0f / (1.0f + __expf(-x)); }

// ---- merged pack: fp32 (rows x 2048) -> bf16 (rows x 4096 at col off) -----
__global__ __launch_bounds__(256) void cvt_all(const float* __restrict__ x,
                                               const float* __restrict__ h,
                                               const float* __restrict__ Wih,
                                               const float* __restrict__ Whh,
                                               unsigned short* __restrict__ Abf,
                                               unsigned short* __restrict__ Wbf) {
  int bid = blockIdx.x;
  const float* src; unsigned short* dst; int col_off; int base;
  if (bid < 4096)        { src = x;   dst = Abf; col_off = 0;    base = bid; }
  else if (bid < 8192)   { src = h;   dst = Abf; col_off = 2048; base = bid - 4096; }
  else if (bid < 24576)  { src = Wih; dst = Wbf; col_off = 0;    base = bid - 8192; }
  else                   { src = Whh; dst = Wbf; col_off = 2048; base = bid - 24576; }
  int i = base * 256 + threadIdx.x;
  int flat = i << 2;
  int r = flat >> 11;
  int c = flat & 2047;
  float4 v = *(const float4*)(src + flat);
  ushort4 o;
  o.x = f2bf(v.x); o.y = f2bf(v.y); o.z = f2bf(v.z); o.w = f2bf(v.w);
  *(ushort4*)(dst + (((size_t)r) << 12) + col_off + c) = o;
}

// ---- fused 256² 8-phase bf16 GEMM + LSTM epilogue --------------------------
// BM=256 M-rows, "BN=256" = 4 gates x 64 h-cols (permuted W rows), BK=64.
// In-tile N-col c = 64q+16g+s  <->  W row g*2048 + h0 + 16q + s.
// Wave wn (0..3) ends up owning gates 0..3 (nt index) for h-cols h0+16*wn+l15.
// LDS 128 KiB: lds[buf2][part4][128*64]; swizzle colbyte ^= (localrow&7)<<4,
// applied on pre-swizzled global SOURCE (stage) and on READ (both-sides).
// Stagger: tile t stages {A0(t+1),A1(t+1),B0(t+2),B1(t+2)} -> vmcnt(4).
__global__ __launch_bounds__(512, 2) void gemm_lstm(
    const unsigned short* __restrict__ A,   // [2048][4096] bf16 = [x|h]
    const unsigned short* __restrict__ W,   // [8192][4096] bf16 = [Wih|Whh]
    const float* __restrict__ b_ih, const float* __restrict__ b_hh,
    const float* __restrict__ C_prev,       // [2048][2048] fp32
    float* __restrict__ out)                // 6 x [2048][2048] fp32
{
  constexpr int K = 4096;
  constexpr int BK = 64;
  constexpr int NT = K / BK;                // 64 K-tiles
  __shared__ alignas(16) unsigned short lds[2][4][128 * 64];  // 128 KiB

  // XCD slab: xc owns 4 h-tiles x all 8 bm-tiles (disjoint W slab)
  int b  = blockIdx.x;
  int xc = b & 7, ii = b >> 3;
  int bm = (ii & 7) * 256;
  int h0 = (xc * 4 + (ii >> 3)) * 64;       // h-tile base (32 tiles of 64)

  int tid  = threadIdx.x;
  int lane = tid & 63;
  int w    = tid >> 6;        // 0..7
  int wm   = w >> 2;          // 0..1 -> A-half
  int wn   = w & 3;           // 0..3 -> B-half wn>>1, sub-row (wn&1)*64
  int l15  = lane & 15;
  int lq   = lane >> 4;       // 0..3

  // swizzled fragment col (elements) for kq=0,1
  int ce0 = ((lq * 16) ^ ((l15 & 7) << 4)) >> 1;
  int ce1 = ((64 + lq * 16) ^ ((l15 & 7) << 4)) >> 1;

  // staging: wave w writes local rows 16w..16w+15 of a half;
  // pre-swizzled source: row_local = 16w + (lane>>3), col = ((l&7)^(l>>3))*8
  int srow_s = lane >> 3;
  int scol = ((lane & 7) ^ (lane >> 3)) * 8;
  const unsigned short* gA = A + (size_t)(bm + 16 * w + srow_s) * K + scol;
  // B: local row 128*hh + 16w + s  ->  W row (w&3)*2048 + h0 + 16*(w>>2) + 32*hh + s
  const unsigned short* gB0 =
      W + (size_t)((w & 3) * 2048 + h0 + 16 * (w >> 2) + srow_s) * K + scol;

  f32x4 acc[8][4] = {};

  auto stageA = [&](int t, int hh) {
    unsigned short* l0 = &lds[t & 1][hh][w * 1024];
    const unsigned short* g = gA + (size_t)hh * 128 * K + t * BK;
    gload_lds16(g, l0);
    gload_lds16(g + (size_t)8 * K, l0 + 512);
  };
  auto stageB = [&](int t, int hh) {
    unsigned short* l0 = &lds[t & 1][2 + hh][w * 1024];
    const unsigned short* g = gB0 + (size_t)hh * 32 * K + t * BK;
    gload_lds16(g, l0);
    gload_lds16(g + (size_t)8 * K, l0 + 512);
  };

  // prologue: tile0 all halves + tile1 B halves
  stageA(0, 0); stageA(0, 1); stageB(0, 0); stageB(0, 1);
  stageB(1, 0); stageB(1, 1);

  bf16x8 af[4][2], bf01[2][2], bf23[2][2];

  for (int t = 0; t < NT; ++t) {
    if (t < NT - 1) asm volatile("s_waitcnt vmcnt(4)" ::: "memory");
    else            asm volatile("s_waitcnt vmcnt(0)" ::: "memory");
    barrier_f();

    const unsigned short* Ab = lds[t & 1][wm];
    const unsigned short* Bb = lds[t & 1][2 + (wn >> 1)];
    int brow = (wn & 1) * 64;

    // ---- P0: read A m0-3 + B n0-1; stage A0(t+1); MFMA m0-3 x n0-1
#pragma unroll
    for (int mt = 0; mt < 4; ++mt) {
      af[mt][0] = *(const bf16x8*)&Ab[(mt * 16 + l15) * 64 + ce0];
      af[mt][1] = *(const bf16x8*)&Ab[(mt * 16 + l15) * 64 + ce1];
    }
#pragma unroll
    for (int nt = 0; nt < 2; ++nt) {
      bf01[nt][0] = *(const bf16x8*)&Bb[(brow + nt * 16 + l15) * 64 + ce0];
      bf01[nt][1] = *(const bf16x8*)&Bb[(brow + nt * 16 + l15) * 64 + ce1];
    }
    if (t + 1 < NT) stageA(t + 1, 0);
    barrier_f();
    __builtin_amdgcn_s_setprio(1);
#pragma unroll
    for (int mt = 0; mt < 4; ++mt)
#pragma unroll
      for (int nt = 0; nt < 2; ++nt) {
        acc[mt][nt] = __builtin_amdgcn_mfma_f32_16x16x32_bf16(af[mt][0], bf01[nt][0], acc[mt][nt], 0, 0, 0);
        acc[mt][nt] = __builtin_amdgcn_mfma_f32_16x16x32_bf16(af[mt][1], bf01[nt][1], acc[mt][nt], 0, 0, 0);
      }
    __builtin_amdgcn_s_setprio(0);
    barrier_f();

    // ---- P1: read B n2-3; stage A1(t+1); MFMA m0-3 x n2-3
#pragma unroll
    for (int nt = 0; nt < 2; ++nt) {
      bf23[nt][0] = *(const bf16x8*)&Bb[(brow + (2 + nt) * 16 + l15) * 64 + ce0];
      bf23[nt][1] = *(const bf16x8*)&Bb[(brow + (2 + nt) * 16 + l15) * 64 + ce1];
    }
    if (t + 1 < NT) stageA(t + 1, 1);
    barrier_f();
    __builtin_amdgcn_s_setprio(1);
#pragma unroll
    for (int mt = 0; mt < 4; ++mt)
#pragma unroll
      for (int nt = 0; nt < 2; ++nt) {
        acc[mt][2 + nt] = __builtin_amdgcn_mfma_f32_16x16x32_bf16(af[mt][0], bf23[nt][0], acc[mt][2 + nt], 0, 0, 0);
        acc[mt][2 + nt] = __builtin_amdgcn_mfma_f32_16x16x32_bf16(af[mt][1], bf23[nt][1], acc[mt][2 + nt], 0, 0, 0);
      }
    __builtin_amdgcn_s_setprio(0);
    barrier_f();

    // ---- P2: read A m4-7; stage B0(t+2); MFMA m4-7 x n2-3
#pragma unroll
    for (int mt = 0; mt < 4; ++mt) {
      af[mt][0] = *(const bf16x8*)&Ab[(64 + mt * 16 + l15) * 64 + ce0];
      af[mt][1] = *(const bf16x8*)&Ab[(64 + mt * 16 + l15) * 64 + ce1];
    }
    if (t + 2 < NT) stageB(t + 2, 0);
    barrier_f();
    __builtin_amdgcn_s_setprio(1);
#pragma unroll
    for (int mt = 0; mt < 4; ++mt)
#pragma unroll
      for (int nt = 0; nt < 2; ++nt) {
        acc[4 + mt][2 + nt] = __builtin_amdgcn_mfma_f32_16x16x32_bf16(af[mt][0], bf23[nt][0], acc[4 + mt][2 + nt], 0, 0, 0);
        acc[4 + mt][2 + nt] = __builtin_amdgcn_mfma_f32_16x16x32_bf16(af[mt][1], bf23[nt][1], acc[4 + mt][2 + nt], 0, 0, 0);
      }
    __builtin_amdgcn_s_setprio(0);
    barrier_f();

    // ---- P3: stage B1(t+2); MFMA m4-7 x n0-1
    if (t + 2 < NT) stageB(t + 2, 1);
    barrier_f();
    __builtin_amdgcn_s_setprio(1);
#pragma unroll
    for (int mt = 0; mt < 4; ++mt)
#pragma unroll
      for (int nt = 0; nt < 2; ++nt) {
        acc[4 + mt][nt] = __builtin_amdgcn_mfma_f32_16x16x32_bf16(af[mt][0], bf01[nt][0], acc[4 + mt][nt], 0, 0, 0);
        acc[4 + mt][nt] = __builtin_amdgcn_mfma_f32_16x16x32_bf16(af[mt][1], bf01[nt][1], acc[4 + mt][nt], 0, 0, 0);
      }
    __builtin_amdgcn_s_setprio(0);
    // next tile's boundary vmcnt+barrier orders P3.
  }

  // ---- fused LSTM epilogue --------------------------------------------
  // nt = gate index (0:i 1:f 2:g 3:o); h-col = h0 + 16*wn + l15.
  // 16x16 C/D: col(lane&15)=s -> h-col; row=(lane>>4)*4+j (m89).
  int hcol = h0 + wn * 16 + l15;
  float cb0 = b_ih[hcol]          + b_hh[hcol];
  float cb1 = b_ih[2048 + hcol]   + b_hh[2048 + hcol];
  float cb2 = b_ih[4096 + hcol]   + b_hh[4096 + hcol];
  float cb3 = b_ih[6144 + hcol]   + b_hh[6144 + hcol];
  constexpr size_t SEC = (size_t)2048 * 2048;
#pragma unroll
  for (int mt = 0; mt < 8; ++mt) {
    int row0 = bm + wm * 128 + mt * 16 + lq * 4;
#pragma unroll
    for (int j = 0; j < 4; ++j) {
      size_t off = (size_t)(row0 + j) * 2048 + hcol;
      float I = sigm(acc[mt][0][j] + cb0);
      float F = sigm(acc[mt][1][j] + cb1);
      float G = tanhf(acc[mt][2][j] + cb2);
      float O = sigm(acc[mt][3][j] + cb3);
      float C = F * C_prev[off] + I * G;
      float H = O * tanhf(C);
      out[0 * SEC + off] = H;
      out[1 * SEC + off] = C;
      out[2 * SEC + off] = F;
      out[3 * SEC + off] = I;
      out[4 * SEC + off] = G;
      out[5 * SEC + off] = O;
    }
  }
}

// ---------------------------------------------------------------------------
extern "C" void kernel_launch(void* const* d_in, const int* in_sizes, int n_in,
                              void* d_out, int out_size, void* d_ws, size_t ws_size,
                              hipStream_t stream) {
  const float* x   = (const float*)d_in[0];
  const float* h   = (const float*)d_in[1];
  const float* Cp  = (const float*)d_in[2];
  const float* Wih = (const float*)d_in[3];
  const float* bih = (const float*)d_in[4];
  const float* Whh = (const float*)d_in[5];
  const float* bhh = (const float*)d_in[6];
  float* out = (float*)d_out;

  uint8_t* ws = (uint8_t*)d_ws;
  unsigned short* Abf  = (unsigned short*)ws;                          // 16 MiB
  unsigned short* Wbf  = (unsigned short*)(ws + (size_t)(16u << 20));  // 64 MiB

  cvt_all<<<40960, 256, 0, stream>>>(x, h, Wih, Whh, Abf, Wbf);
  gemm_lstm<<<256, 512, 0, stream>>>(Abf, Wbf, bih, bhh, Cp, out);
}